// Round 1
// baseline (400.822 us; speedup 1.0000x reference)
//
#include <hip/hip_runtime.h>
#include <math.h>

#define NQ 12
#define NSTATE 4096          // 2^12
#define DEPTH 3
#define FEAT 768
#define NCLS 10
#define PI_HALF 1.57079632679489662f

__global__ __launch_bounds__(256) void qcircuit_fused(
    const float* __restrict__ x,    // [B, 768]
    const float* __restrict__ Wp,   // [12, 768]
    const float* __restrict__ w,    // [3, 12, 3]
    const float* __restrict__ Wo,   // [10, 12]
    const float* __restrict__ bo,   // [10]
    float* __restrict__ out)        // [B, 10]
{
    __shared__ float2 st[NSTATE];          // 32 KB statevector
    __shared__ float red[4][NQ];           // per-wave reduction partials
    __shared__ float ang_c[NQ], ang_s[NQ]; // RY cos/sin per wire (per-sample)
    __shared__ float rotm[DEPTH * NQ][8];  // Rot matrices (batch-independent)
    __shared__ float zsh[NQ];              // PauliZ expectations

    const int b = blockIdx.x;
    const int t = threadIdx.x;
    const int wave = t >> 6;
    const int lane = t & 63;

    // ---------------- angles: acc[q] = x[b,:] . Wp[q,:] ----------------
    float acc[NQ];
    #pragma unroll
    for (int q = 0; q < NQ; ++q) acc[q] = 0.f;
    const float* xr = x + (size_t)b * FEAT;
    #pragma unroll
    for (int k = 0; k < FEAT / 256; ++k) {
        int i = t + 256 * k;
        float xi = xr[i];
        #pragma unroll
        for (int q = 0; q < NQ; ++q) acc[q] = fmaf(xi, Wp[q * FEAT + i], acc[q]);
    }
    #pragma unroll
    for (int q = 0; q < NQ; ++q) {
        float v = acc[q];
        #pragma unroll
        for (int off = 32; off > 0; off >>= 1) v += __shfl_down(v, off, 64);
        acc[q] = v;
    }
    if (lane == 0) {
        #pragma unroll
        for (int q = 0; q < NQ; ++q) red[wave][q] = acc[q];
    }
    __syncthreads();

    if (t < NQ) {
        float s = red[0][t] + red[1][t] + red[2][t] + red[3][t];
        float angle = tanhf(s) * PI_HALF;
        float h = 0.5f * angle;
        ang_c[t] = cosf(h);
        ang_s[t] = sinf(h);
    }
    // Rot matrices: m00,m01,m10,m11 (complex), batch-independent
    if (t < DEPTH * NQ) {
        float phi = w[t * 3 + 0], th = w[t * 3 + 1], om = w[t * 3 + 2];
        float ct = cosf(0.5f * th), sn = sinf(0.5f * th);
        float a0 = -0.5f * (phi + om);     // e^{+i a0} = e^{-i(phi+om)/2}
        float a1 = 0.5f * (phi - om);      // e^{+i a1} = e^{ i(phi-om)/2}
        float c0 = cosf(a0), s0 = sinf(a0);
        float c1 = cosf(a1), s1 = sinf(a1);
        rotm[t][0] = c0 * ct;  rotm[t][1] = s0 * ct;    // m00 = e^{-i(phi+om)/2} c
        rotm[t][2] = -c1 * sn; rotm[t][3] = -s1 * sn;   // m01 = -e^{i(phi-om)/2} s
        rotm[t][4] = c1 * sn;  rotm[t][5] = -s1 * sn;   // m10 = e^{-i(phi-om)/2} s
        rotm[t][6] = c0 * ct;  rotm[t][7] = -s0 * ct;   // m11 = e^{i(phi+om)/2} c
    }
    // init |0...0>
    #pragma unroll
    for (int k = 0; k < NSTATE / 256; ++k) {
        int i = t + 256 * k;
        st[i] = make_float2(i == 0 ? 1.f : 0.f, 0.f);
    }
    __syncthreads();

    // ---------------- RY encoding layer (real 2x2) ----------------
    for (int q = 0; q < NQ; ++q) {
        const int mask = 1 << (NQ - 1 - q);   // wire 0 = MSB
        const float c = ang_c[q], s = ang_s[q];
        #pragma unroll
        for (int k = 0; k < (NSTATE / 2) / 256; ++k) {
            int p = t + 256 * k;                               // 0..2047
            int i0 = ((p & ~(mask - 1)) << 1) | (p & (mask - 1));
            int i1 = i0 | mask;
            float2 v0 = st[i0], v1 = st[i1];
            st[i0] = make_float2(c * v0.x - s * v1.x, c * v0.y - s * v1.y);
            st[i1] = make_float2(s * v0.x + c * v1.x, s * v0.y + c * v1.y);
        }
        __syncthreads();
    }

    // ---------------- StronglyEntanglingLayers ----------------
    for (int l = 0; l < DEPTH; ++l) {
        for (int q = 0; q < NQ; ++q) {
            const float* m = rotm[l * NQ + q];
            float m00r = m[0], m00i = m[1], m01r = m[2], m01i = m[3];
            float m10r = m[4], m10i = m[5], m11r = m[6], m11i = m[7];
            const int mask = 1 << (NQ - 1 - q);
            #pragma unroll
            for (int k = 0; k < (NSTATE / 2) / 256; ++k) {
                int p = t + 256 * k;
                int i0 = ((p & ~(mask - 1)) << 1) | (p & (mask - 1));
                int i1 = i0 | mask;
                float2 v0 = st[i0], v1 = st[i1];
                float nr0 = m00r * v0.x - m00i * v0.y + m01r * v1.x - m01i * v1.y;
                float ni0 = m00r * v0.y + m00i * v0.x + m01r * v1.y + m01i * v1.x;
                float nr1 = m10r * v0.x - m10i * v0.y + m11r * v1.x - m11i * v1.y;
                float ni1 = m10r * v0.y + m10i * v0.x + m11r * v1.y + m11i * v1.x;
                st[i0] = make_float2(nr0, ni0);
                st[i1] = make_float2(nr1, ni1);
            }
            __syncthreads();
        }
        const int r = l % (NQ - 1) + 1;   // PennyLane default ranges
        for (int q = 0; q < NQ; ++q) {
            const int tq = (q + r) % NQ;
            const int mc = 1 << (NQ - 1 - q);
            const int mt = 1 << (NQ - 1 - tq);
            const int mlo = mc < mt ? mc : mt;
            const int mhi = mc < mt ? mt : mc;
            #pragma unroll
            for (int k = 0; k < (NSTATE / 4) / 256; ++k) {
                int p = t + 256 * k;                               // 0..1023
                int i = ((p & ~(mlo - 1)) << 1) | (p & (mlo - 1)); // insert 0 @ mlo
                i = ((i & ~(mhi - 1)) << 1) | (i & (mhi - 1));     // insert 0 @ mhi
                int i0 = i | mc;        // ctrl=1, tgt=0
                int i1 = i0 | mt;       // ctrl=1, tgt=1
                float2 a = st[i0], bb = st[i1];
                st[i0] = bb;
                st[i1] = a;
            }
            __syncthreads();
        }
    }

    // ---------------- PauliZ expectations ----------------
    float zacc[NQ];
    #pragma unroll
    for (int q = 0; q < NQ; ++q) zacc[q] = 0.f;
    #pragma unroll
    for (int k = 0; k < NSTATE / 256; ++k) {
        int i = t + 256 * k;
        float2 v = st[i];
        float p = v.x * v.x + v.y * v.y;
        #pragma unroll
        for (int q = 0; q < NQ; ++q) {
            float sign = ((i >> (NQ - 1 - q)) & 1) ? -1.f : 1.f;
            zacc[q] = fmaf(sign, p, zacc[q]);
        }
    }
    #pragma unroll
    for (int q = 0; q < NQ; ++q) {
        float v = zacc[q];
        #pragma unroll
        for (int off = 32; off > 0; off >>= 1) v += __shfl_down(v, off, 64);
        zacc[q] = v;
    }
    __syncthreads();   // red[] reuse safety
    if (lane == 0) {
        #pragma unroll
        for (int q = 0; q < NQ; ++q) red[wave][q] = zacc[q];
    }
    __syncthreads();
    if (t < NQ) zsh[t] = red[0][t] + red[1][t] + red[2][t] + red[3][t];
    __syncthreads();

    // ---------------- output head: out[b,c] = z . Wo[c,:] + bo[c] ----------------
    if (t < NCLS) {
        float s = bo[t];
        #pragma unroll
        for (int q = 0; q < NQ; ++q) s = fmaf(zsh[q], Wo[t * NQ + q], s);
        out[(size_t)b * NCLS + t] = s;
    }
}

extern "C" void kernel_launch(void* const* d_in, const int* in_sizes, int n_in,
                              void* d_out, int out_size, void* d_ws, size_t ws_size,
                              hipStream_t stream) {
    const float* x  = (const float*)d_in[0];   // [B,768]
    const float* Wp = (const float*)d_in[1];   // [12,768]
    const float* w  = (const float*)d_in[2];   // [3,12,3]
    const float* Wo = (const float*)d_in[3];   // [10,12]
    const float* bo = (const float*)d_in[4];   // [10]
    float* out = (float*)d_out;

    const int B = in_sizes[0] / FEAT;          // 4096
    qcircuit_fused<<<B, 256, 0, stream>>>(x, Wp, w, Wo, bo, out);
}